// Round 1
// 263.823 us; speedup vs baseline: 1.0175x; 1.0175x over previous
//
#include <hip/hip_runtime.h>
#include <math.h>

#define EPS 1e-8f

typedef float nfloat4 __attribute__((ext_vector_type(4)));

__device__ __forceinline__ float softplus_f(float x) {
    return (x > 20.0f) ? x : log1pf(expf(x));
}
__device__ __forceinline__ float sigmoid_f(float x) {
    return 1.0f / (1.0f + expf(-x));
}

// controls per b (792 floats): keys[4][64] | erase[4][64] | write[4][64]
//   | betas[4] | gates[4] | shifts[4][3] | gammas[4]

// -------------------------------------------------------------------------
// Kernel 1: e[b,h,n] = exp(beta_h*cos(key_h, mem[b,n]) - beta_h)
// (uniform shift by -beta <= -max possible score: cancels in softmax,
//  bounds e in (0,1] so no overflow; removes the global max pass entirely)
// Also emits per-tile partial sums S_part[b,h,tile] (tile = 128 rows).
// block = 256 threads; 128 rows/block; grid = (N/128, B).
// -------------------------------------------------------------------------
__global__ __launch_bounds__(256)
void score_kernel(const float* __restrict__ memory,
                  const float* __restrict__ controls,
                  float* __restrict__ evals,
                  float* __restrict__ S_part, int N)
{
    int b = blockIdx.y;
    int tile = blockIdx.x;
    int nbase = tile * 128;
    int t = threadIdx.x;
    int rq = t >> 4;      // 0..15
    int lane = t & 15;    // 0..15
    int ntiles = N >> 7;

    __shared__ float kk[256];
    __shared__ float betas_s[4], knorm_s[4];
    __shared__ float sc[4][128];

    const float* c = controls + (size_t)b * 792;

    // per-block key prep: wave h handles head h (h = t>>6, w = t&63)
    {
        int h = t >> 6, w = t & 63;
        float kt = tanhf(c[h * 64 + w]);
        kk[h * 64 + w] = kt;
        float nsq = kt * kt;
        #pragma unroll
        for (int m = 1; m < 64; m <<= 1) nsq += __shfl_xor(nsq, m, 64);
        if (w == 0) knorm_s[h] = sqrtf(nsq);
        if (t < 4)  betas_s[t] = softplus_f(c[768 + t]);
    }
    __syncthreads();

    float4 k4[4];
    #pragma unroll
    for (int h = 0; h < 4; h++) k4[h] = ((const float4*)(kk + h * 64))[lane];
    float beta_l[4], knorm_l[4];
    #pragma unroll
    for (int h = 0; h < 4; h++) { beta_l[h] = betas_s[h]; knorm_l[h] = knorm_s[h]; }

    // prefetch 8 rows (independent loads in flight)
    float4 m4[8];
    #pragma unroll
    for (int j = 0; j < 8; j++) {
        int n = nbase + rq + 16 * j;
        m4[j] = ((const float4*)(memory + ((size_t)b * N + n) * 64))[lane];
    }

    #pragma unroll
    for (int j = 0; j < 8; j++) {
        float nsq = m4[j].x * m4[j].x + m4[j].y * m4[j].y
                  + m4[j].z * m4[j].z + m4[j].w * m4[j].w;
        float d[4];
        #pragma unroll
        for (int h = 0; h < 4; h++) {
            d[h] = m4[j].x * k4[h].x + m4[j].y * k4[h].y
                 + m4[j].z * k4[h].z + m4[j].w * k4[h].w;
        }
        #pragma unroll
        for (int m = 1; m < 16; m <<= 1) {
            nsq += __shfl_xor(nsq, m, 64);
            #pragma unroll
            for (int h = 0; h < 4; h++) d[h] += __shfl_xor(d[h], m, 64);
        }
        if (lane == 0) {
            float mn = sqrtf(nsq);
            int row = rq + 16 * j;
            #pragma unroll
            for (int h = 0; h < 4; h++) {
                float s = beta_l[h] * d[h] / (mn * knorm_l[h] + EPS);
                sc[h][row] = __expf(s - beta_l[h]);   // bounded (0,1]
            }
        }
    }
    __syncthreads();

    // 512 values out: 256 threads x 2, coalesced in 128-float runs
    #pragma unroll
    for (int k = 0; k < 2; k++) {
        int idx = t + k * 256;
        int h = idx >> 7, i = idx & 127;
        evals[((size_t)b * 4 + h) * N + nbase + i] = sc[h][i];
    }

    // per-tile partial sum per head: wave h sums its 128 e-values
    {
        int h = t >> 6, w = t & 63;
        float v = sc[h][w] + sc[h][w + 64];
        #pragma unroll
        for (int m = 1; m < 64; m <<= 1) v += __shfl_xor(v, m, 64);
        if (w == 0) S_part[((size_t)b * 4 + h) * ntiles + tile] = v;
    }
}

// -------------------------------------------------------------------------
// Kernel 2 (replaces the latency-bound 1024-thread weights_kernel):
// streaming interp -> circular 3-tap shift -> sharpen.
// Each block = one 2048-element chunk of one (b,h) row; 256 thr x 8 elems.
// S = sum of 64 tile partials (one wave reduce). The 8 w_interp values a
// thread owns stay in registers; only the 2 edge neighbors come from LDS.
// Emits unnormalized w^gamma plus per-chunk partials T_part[b,h,chunk];
// the final 1/(T+EPS) normalize is folded into the output kernel.
// grid = B*4*(N/2048), full occupancy.
// -------------------------------------------------------------------------
__global__ __launch_bounds__(256)
void shift_kernel(const float* __restrict__ evals,
                  const float* __restrict__ prev,
                  const float* __restrict__ controls,
                  const float* __restrict__ S_part,
                  float* __restrict__ wp,
                  float* __restrict__ T_part, int N)
{
    int CH = N >> 11;                    // 2048-element chunks per row
    int bh = blockIdx.x / CH;
    int chunk = blockIdx.x - bh * CH;
    int b = bh >> 2, h = bh & 3;
    int t = threadIdx.x;
    int ntiles = N >> 7;
    const float* c = controls + (size_t)b * 792;

    __shared__ float wl[2050];
    __shared__ float redm[4];
    __shared__ float Ssh;

    // S[b,h] = sum of tile partials (wave 0 only)
    if (t < 64) {
        float v = 0.0f;
        for (int i = t; i < ntiles; i += 64) v += S_part[(size_t)bh * ntiles + i];
        #pragma unroll
        for (int m = 1; m < 64; m <<= 1) v += __shfl_xor(v, m, 64);
        if (t == 0) Ssh = v;
    }

    float gate  = sigmoid_f(c[772 + h]);
    float r0 = c[776 + h * 3 + 0];
    float r1 = c[776 + h * 3 + 1];
    float r2 = c[776 + h * 3 + 2];
    float rmx = fmaxf(r0, fmaxf(r1, r2));
    float e0 = expf(r0 - rmx), e1 = expf(r1 - rmx), e2 = expf(r2 - rmx);
    float sinv = 1.0f / (e0 + e1 + e2);
    float s0 = e0 * sinv, s1 = e1 * sinv, s2 = e2 * sinv;
    float gamma = 1.0f + softplus_f(c[788 + h]);

    const float* erow = evals + (size_t)bh * N;
    const float* prow = prev  + (size_t)bh * N;
    int base = chunk << 11;
    int li = t << 3;                     // local index of first owned element

    float4 ea = ((const float4*)(erow + base))[2 * t];
    float4 eb = ((const float4*)(erow + base))[2 * t + 1];
    float4 pa = ((const float4*)(prow + base))[2 * t];
    float4 pb = ((const float4*)(prow + base))[2 * t + 1];

    __syncthreads();                     // Ssh ready
    float invS = 1.0f / Ssh;
    float og = 1.0f - gate;

    float w[8];
    w[0] = gate * ea.x * invS + og * pa.x;
    w[1] = gate * ea.y * invS + og * pa.y;
    w[2] = gate * ea.z * invS + og * pa.z;
    w[3] = gate * ea.w * invS + og * pa.w;
    w[4] = gate * eb.x * invS + og * pb.x;
    w[5] = gate * eb.y * invS + og * pb.y;
    w[6] = gate * eb.z * invS + og * pb.z;
    w[7] = gate * eb.w * invS + og * pb.w;

    // wl[1+j] = w_interp[base+j]; wl[0]/wl[2049] = circular halo
    #pragma unroll
    for (int k = 0; k < 8; k++) wl[1 + li + k] = w[k];
    if (t == 0) {
        int g = base - 1; if (g < 0) g += N;
        wl[0] = gate * erow[g] * invS + og * prow[g];
    }
    if (t == 255) {
        int g = base + 2048; if (g >= N) g -= N;
        wl[2049] = gate * erow[g] * invS + og * prow[g];
    }
    __syncthreads();

    float nb[10];
    nb[0] = wl[li];                      // w_interp[base+li-1]
    #pragma unroll
    for (int k = 0; k < 8; k++) nb[k + 1] = w[k];
    nb[9] = wl[li + 9];                  // w_interp[base+li+8]

    float o[8];
    float acc = 0.0f;
    #pragma unroll
    for (int k = 0; k < 8; k++) {
        float ws = s0 * nb[k] + s1 * nb[k + 1] + s2 * nb[k + 2];
        // ws strictly > 0 (softmax>0, prev>=0, gate in (0,1)) -> fast pow
        float v = __expf(gamma * __logf(ws));
        o[k] = v; acc += v;
    }

    #pragma unroll
    for (int m = 1; m < 64; m <<= 1) acc += __shfl_xor(acc, m, 64);
    if ((t & 63) == 0) redm[t >> 6] = acc;
    __syncthreads();
    if (t == 0) T_part[(size_t)bh * CH + chunk] = redm[0] + redm[1] + redm[2] + redm[3];

    float4 oa = make_float4(o[0], o[1], o[2], o[3]);
    float4 ob = make_float4(o[4], o[5], o[6], o[7]);
    ((float4*)(wp + (size_t)bh * N + base))[2 * t] = oa;
    ((float4*)(wp + (size_t)bh * N + base))[2 * t + 1] = ob;
}

// -------------------------------------------------------------------------
// Kernel 3: out[b,n,w] = mem * prod_h(1 - wd[h,n]*erase[h,w]) + sum_h wd*write
// wd = wp * 1/(T+EPS): normalization folded in at the wd_s staging load.
// block = 256 threads; 128 rows/block; 8 rows/thread.
// Non-temporal out stores: keep L3 for memory[] (L3-hot from kernel 1).
// grid = B * N/128.
// -------------------------------------------------------------------------
__global__ __launch_bounds__(256)
void output_kernel(const float* __restrict__ memory,
                   const float* __restrict__ wdist,
                   const float* __restrict__ T_part,
                   const float* __restrict__ controls,
                   float* __restrict__ out, int N)
{
    int t = threadIdx.x;
    int blocksPerB = N >> 7;
    int b = blockIdx.x / blocksPerB;
    int nbase = (blockIdx.x % blocksPerB) << 7;
    int CH = N >> 11;

    __shared__ float es[256], wv[256], wd_s[512], invT_s[4];
    const float* c = controls + (size_t)b * 792;
    if (t < 4) {
        float s = 0.0f;
        for (int cc = 0; cc < CH; cc++) s += T_part[((size_t)b * 4 + t) * CH + cc];
        invT_s[t] = 1.0f / (s + EPS);
    }
    es[t] = sigmoid_f(c[256 + t]);
    wv[t] = tanhf(c[512 + t]);
    __syncthreads();
    #pragma unroll
    for (int k = 0; k < 2; k++) {
        int idx = t + k * 256;
        int h = idx >> 7, i = idx & 127;
        wd_s[idx] = wdist[((size_t)b * 4 + h) * N + nbase + i] * invT_s[h];
    }
    __syncthreads();

    int rq = t >> 4, lane = t & 15;

    float4 e4[4], w4[4];
    #pragma unroll
    for (int h = 0; h < 4; h++) {
        e4[h] = ((const float4*)(es + h * 64))[lane];
        w4[h] = ((const float4*)(wv + h * 64))[lane];
    }

    float4 m4[8];
    #pragma unroll
    for (int j = 0; j < 8; j++) {
        int n = nbase + rq + 16 * j;
        m4[j] = ((const float4*)(memory + ((size_t)b * N + n) * 64))[lane];
    }

    #pragma unroll
    for (int j = 0; j < 8; j++) {
        int row = rq + 16 * j;
        int n = nbase + row;
        float4 pe = make_float4(1.f, 1.f, 1.f, 1.f);
        float4 up = make_float4(0.f, 0.f, 0.f, 0.f);
        #pragma unroll
        for (int h = 0; h < 4; h++) {
            float f = wd_s[h * 128 + row];
            pe.x *= 1.0f - f * e4[h].x;  pe.y *= 1.0f - f * e4[h].y;
            pe.z *= 1.0f - f * e4[h].z;  pe.w *= 1.0f - f * e4[h].w;
            up.x += f * w4[h].x;  up.y += f * w4[h].y;
            up.z += f * w4[h].z;  up.w += f * w4[h].w;
        }
        nfloat4 o;
        o.x = m4[j].x * pe.x + up.x;
        o.y = m4[j].y * pe.y + up.y;
        o.z = m4[j].z * pe.z + up.z;
        o.w = m4[j].w * pe.w + up.w;
        nfloat4* op = ((nfloat4*)(out + ((size_t)b * N + n) * 64)) + lane;
        __builtin_nontemporal_store(o, op);
    }
}

// -------------------------------------------------------------------------
extern "C" void kernel_launch(void* const* d_in, const int* in_sizes, int n_in,
                              void* d_out, int out_size, void* d_ws, size_t ws_size,
                              hipStream_t stream) {
    const float* memory   = (const float*)d_in[0];
    const float* controls = (const float*)d_in[1];
    const float* prev     = (const float*)d_in[2];
    float* out = (float*)d_out;

    int B = in_sizes[1] / 792;            // H*(3W+6) = 792
    int N = in_sizes[0] / (B * 64);       // W = 64
    int ntiles = N >> 7;                  // 128-row tiles
    int CH = N >> 11;                     // 2048-elem chunks

    // workspace layout (floats): evals | wp | S_part | T_part
    float* evals  = (float*)d_ws;                       // B*4*N
    float* wp     = evals + (size_t)B * 4 * N;          // B*4*N
    float* S_part = wp + (size_t)B * 4 * N;             // B*4*ntiles
    float* T_part = S_part + (size_t)B * 4 * ntiles;    // B*4*CH

    score_kernel<<<dim3(ntiles, B), 256, 0, stream>>>(memory, controls, evals, S_part, N);
    shift_kernel<<<B * 4 * CH, 256, 0, stream>>>(evals, prev, controls, S_part, wp, T_part, N);
    output_kernel<<<B * ntiles, 256, 0, stream>>>(memory, wp, T_part, controls, out, N);
}